// Round 1
// 98.963 us; speedup vs baseline: 1.0086x; 1.0086x over previous
//
#include <hip/hip_runtime.h>
#include <hip/hip_bf16.h>

#define NVOX 100000
#define CIN 32
#define COUT 32
#define KOFF 27
#define NTILE 6250            // NVOX / 16 exactly
#define SENTE (NVOX << 6)     // encoded zero-row (masked) sentinel

typedef __attribute__((ext_vector_type(8))) short short8;
typedef __attribute__((ext_vector_type(4))) float float4v;
typedef __attribute__((ext_vector_type(4))) int   int4v;

// fp32 -> bf16 round-to-nearest-even (finite inputs)
__device__ __forceinline__ short f2bf(float x) {
    union { float f; unsigned u; } v; v.f = x;
    unsigned u = v.u;
    u += 0x7FFFu + ((u >> 16) & 1u);
    return (short)(u >> 16);
}

#define FEAT_BLOCKS 3126      // ceil((NVOX+1)*CIN/4 / 256)

// ---- fused pre-pass: features fp32->bf16 (+zero row) AND weight B-fragments ----
__global__ __launch_bounds__(256) void cvt_kernel(
    const float* __restrict__ feat, const float* __restrict__ weight,
    unsigned short* __restrict__ fbf, short8* __restrict__ wfrag)
{
    if (blockIdx.x < FEAT_BLOCKS) {
        int i = (blockIdx.x * 256 + threadIdx.x) * 4;
        if (i < NVOX * CIN) {
            float4v f = *(const float4v*)(feat + i);
            short s[4] = { f2bf(f.x), f2bf(f.y), f2bf(f.z), f2bf(f.w) };
            *(ulonglong1*)(fbf + i) = *(ulonglong1*)s;
        } else if (i < (NVOX + 1) * CIN) {
            short s[4] = { 0, 0, 0, 0 };           // zero row for masked gathers
            *(ulonglong1*)(fbf + i) = *(ulonglong1*)s;
        }
    } else {
        // wfrag[k*128 + t*64 + ln][j] = W[k][ci=(ln>>4)*8+j][co=t*16+(ln&15)]
        int g = (blockIdx.x - FEAT_BLOCKS) * 256 + threadIdx.x;
        if (g >= KOFF * 2 * 64) return;
        int k   = g >> 7;
        int rem = g & 127;
        int t   = rem >> 6;
        int ln  = rem & 63;
        int co  = t * 16 + (ln & 15);
        int cib = (ln >> 4) * 8;
        const float* wp = weight + (k * CIN + cib) * COUT + co;
        short8 b;
#pragma unroll
        for (int j = 0; j < 8; ++j) b[j] = f2bf(wp[j * COUT]);
        wfrag[g] = b;
    }
}

__global__ __launch_bounds__(512, 4) void subm_conv_kernel(
    const unsigned short* __restrict__ fbf,   // bf16 features [N+1,32] (ws)
    const short8* __restrict__ wfrag,         // bf16 B-fragments (ws)
    const float* __restrict__ bias,           // fp32 [32]
    const int* __restrict__ nbr_idx,          // int32 [N,27]
    const int* __restrict__ nbr_mask,         // bool -> int32 [N,27]
    float* __restrict__ out)                  // fp32 [N,32]
{
    __shared__ short8 wlds[KOFF * 2 * 64];    // 55,296 B; reused: meta stage -> weights -> store buffer

    const int tid  = threadIdx.x;
    const int lane = tid & 63;
    const int wave = tid >> 6;                 // 0..7
    const int m    = lane & 15;
    const int quad = lane >> 4;
    const int tile0 = blockIdx.x * 8 + wave;   // 16 voxels per wave
    const bool tv  = tile0 < NTILE;
    const int tile = tv ? tile0 : (NTILE - 1); // clamp whole wave (no OOB, no store)
    const int v0   = tile * 16;

    // ---- Phase A: wave-coalesced metadata load -> enc -> LDS (padded 28-int rows) ----
    // Tile metadata = 432 contiguous ints per array, base 16B-aligned (v0*27*4 = tile*1728).
    // Replaces 54 scattered dword loads/lane with 4 dwordx4 loads/lane.
    int* meta = (int*)wlds + wave * 448;       // 448 ints = 16 voxels * 28 (pad -> 16B-aligned rows)
    {
        const int tb = v0 * KOFF;
        const int j0 = lane * 4;
        int4v ia = *(const int4v*)(nbr_idx  + tb + j0);
        int4v ma = *(const int4v*)(nbr_mask + tb + j0);
#pragma unroll
        for (int c = 0; c < 4; ++c) {
            int j = j0 + c;                    // 0..255
            meta[(j / 27) * 28 + (j % 27)] = (ma[c] ? ia[c] : NVOX) << 6;
        }
        if (j0 < 176) {                        // lanes 0..43 cover j = 256..431
            int4v ib = *(const int4v*)(nbr_idx  + tb + 256 + j0);
            int4v mb = *(const int4v*)(nbr_mask + tb + 256 + j0);
#pragma unroll
            for (int c = 0; c < 4; ++c) {
                int j = 256 + j0 + c;
                meta[(j / 27) * 28 + (j % 27)] = (mb[c] ? ib[c] : NVOX) << 6;
            }
        }
    }

    // readback own voxel's 27 enc values (wave-local write->read; in-order DS pipe + auto lgkmcnt)
    int enc[28];
    {
        const int4v* mp = (const int4v*)(meta + m * 28);   // m*112 B: 16B-aligned, 2-way bank alias (free)
#pragma unroll
        for (int i = 0; i < 7; ++i) {
            int4v t = mp[i];
            enc[i * 4 + 0] = t.x; enc[i * 4 + 1] = t.y;
            enc[i * 4 + 2] = t.z; enc[i * 4 + 3] = t.w;
        }
    }

    // ---- sparsity bitmask: bit k set iff ANY of the wave's 16 voxels has an active k-neighbor ----
    // Density ~4.8% => E[active k] ~ 15.1 of 27. Skipping all-masked k is bit-exact (A rows all zero).
    unsigned bmv = 0;
#pragma unroll
    for (int k = 0; k < KOFF; ++k)
        bmv |= (__any(enc[k] != SENTE) ? 1u : 0u) << k;
    const unsigned bm = (unsigned)__builtin_amdgcn_readfirstlane((int)bmv);

    __syncthreads();                           // all waves done reading meta region
    for (int g = tid; g < KOFF * 2 * 64; g += 512) wlds[g] = wfrag[g];
    __syncthreads();

    float4v acc0 = {0.f, 0.f, 0.f, 0.f};
    float4v acc1 = {0.f, 0.f, 0.f, 0.f};

    const char* fb   = (const char*)fbf;
    const int   boff = quad * 16;              // byte offset of A-frag in row

    // ---- depth-8 rotating gather pipeline, fully unrolled (static slots preserved) ----
    // Gathers stay unconditional: inactive-k gathers hit the single zero row (1 line, L1-hit).
    short8 abuf[8];
#pragma unroll
    for (int k = 0; k < 8; ++k)
        abuf[k] = *(const short8*)(fb + (size_t)(unsigned)enc[k] + boff);

#pragma unroll
    for (int k = 0; k < KOFF; ++k) {
        const int slot = k & 7;
        short8 a = abuf[slot];
        if (k + 8 < KOFF)
            abuf[slot] = *(const short8*)(fb + (size_t)(unsigned)enc[k + 8] + boff);

        if (bm & (1u << k)) {                  // wave-uniform scalar branch (s_and + s_cbranch)
            short8 wb0 = wlds[k * 128 + lane];
            short8 wb1 = wlds[k * 128 + 64 + lane];
            acc0 = __builtin_amdgcn_mfma_f32_16x16x32_bf16(a, wb0, acc0, 0, 0, 0);
            acc1 = __builtin_amdgcn_mfma_f32_16x16x32_bf16(a, wb1, acc1, 0, 0, 0);
        }
    }

    // ---- coalesced epilogue: transpose through LDS, store full 128B rows ----
    __syncthreads();                           // wlds reads done; safe to reuse
    float* tb = (float*)wlds + wave * (16 * 36);   // 16 rows, stride 36 (pad: 2-way banks)

    const float bs0 = bias[m];
    const float bs1 = bias[16 + m];
    if (tv) {
        // C/D layout: col (cout) = lane&15, row (voxel) = quad*4 + reg
#pragma unroll
        for (int r = 0; r < 4; ++r) {
            tb[(quad * 4 + r) * 36 + m]      = acc0[r] + bs0;
            tb[(quad * 4 + r) * 36 + 16 + m] = acc1[r] + bs1;
        }
#pragma unroll
        for (int p = 0; p < 2; ++p) {
            int flat = p * 64 + lane;          // 0..127
            int row  = flat >> 3;              // 8 lanes per 128B row
            int ch   = flat & 7;               // 16B chunk within row
            float4v val = *(const float4v*)(tb + row * 36 + ch * 4);
            *(float4v*)(out + (size_t)(v0 + row) * COUT + ch * 4) = val;
        }
    }
}

extern "C" void kernel_launch(void* const* d_in, const int* in_sizes, int n_in,
                              void* d_out, int out_size, void* d_ws, size_t ws_size,
                              hipStream_t stream) {
    const float* feat = (const float*)d_in[0];
    const float* wgt  = (const float*)d_in[1];
    const float* bias = (const float*)d_in[2];
    const int*   nidx = (const int*)d_in[3];
    const int*   nmsk = (const int*)d_in[4];
    float*       out  = (float*)d_out;

    char* ws = (char*)d_ws;
    unsigned short* fbf   = (unsigned short*)ws;                 // 6,400,064 B
    short8*         wfrag = (short8*)(ws + 6400128);             //    55,296 B

    const int wgt_blocks = (KOFF * 2 * 64 + 255) / 256;          // 14
    cvt_kernel<<<FEAT_BLOCKS + wgt_blocks, 256, 0, stream>>>(feat, wgt, fbf, wfrag);

    const int block = 512;                         // 8 waves = 8 tiles = 128 voxels
    const int grid  = (NTILE + 7) / 8;             // 782
    subm_conv_kernel<<<grid, block, 0, stream>>>(fbf, wfrag, bias, nidx, nmsk, out);
}

// Round 2
// 98.477 us; speedup vs baseline: 1.0136x; 1.0049x over previous
//
#include <hip/hip_runtime.h>
#include <hip/hip_bf16.h>

#define NVOX 100000
#define CIN 32
#define COUT 32
#define KOFF 27
#define NTILE 6250            // NVOX / 16 exactly
#define SENTE (NVOX << 6)     // encoded zero-row (masked) sentinel

typedef __attribute__((ext_vector_type(8))) short short8;
typedef __attribute__((ext_vector_type(4))) float float4v;
typedef __attribute__((ext_vector_type(4))) int   int4v;

// fp32 -> bf16 round-to-nearest-even (finite inputs)
__device__ __forceinline__ short f2bf(float x) {
    union { float f; unsigned u; } v; v.f = x;
    unsigned u = v.u;
    u += 0x7FFFu + ((u >> 16) & 1u);
    return (short)(u >> 16);
}

#define FEAT_BLOCKS 3126      // ceil((NVOX+1)*CIN/4 / 256)

// ---- fused pre-pass: features fp32->bf16 (+zero row) AND weight B-fragments ----
__global__ __launch_bounds__(256) void cvt_kernel(
    const float* __restrict__ feat, const float* __restrict__ weight,
    unsigned short* __restrict__ fbf, short8* __restrict__ wfrag)
{
    if (blockIdx.x < FEAT_BLOCKS) {
        int i = (blockIdx.x * 256 + threadIdx.x) * 4;
        if (i < NVOX * CIN) {
            float4v f = *(const float4v*)(feat + i);
            short s[4] = { f2bf(f.x), f2bf(f.y), f2bf(f.z), f2bf(f.w) };
            *(ulonglong1*)(fbf + i) = *(ulonglong1*)s;
        } else if (i < (NVOX + 1) * CIN) {
            short s[4] = { 0, 0, 0, 0 };           // zero row for masked gathers
            *(ulonglong1*)(fbf + i) = *(ulonglong1*)s;
        }
    } else {
        // wfrag[k*128 + t*64 + ln][j] = W[k][ci=(ln>>4)*8+j][co=t*16+(ln&15)]
        int g = (blockIdx.x - FEAT_BLOCKS) * 256 + threadIdx.x;
        if (g >= KOFF * 2 * 64) return;
        int k   = g >> 7;
        int rem = g & 127;
        int t   = rem >> 6;
        int ln  = rem & 63;
        int co  = t * 16 + (ln & 15);
        int cib = (ln >> 4) * 8;
        const float* wp = weight + (k * CIN + cib) * COUT + co;
        short8 b;
#pragma unroll
        for (int j = 0; j < 8; ++j) b[j] = f2bf(wp[j * COUT]);
        wfrag[g] = b;
    }
}

__global__ __launch_bounds__(512, 4) void subm_conv_kernel(
    const unsigned short* __restrict__ fbf,   // bf16 features [N+1,32] (ws)
    const short8* __restrict__ wfrag,         // bf16 B-fragments (ws)
    const float* __restrict__ bias,           // fp32 [32]
    const int* __restrict__ nbr_idx,          // int32 [N,27]
    const int* __restrict__ nbr_mask,         // bool -> int32 [N,27]
    float* __restrict__ out)                  // fp32 [N,32]
{
    __shared__ short8 wlds[KOFF * 2 * 64];    // 55,296 B: weight fragments only
    __shared__ int    mstore[8 * 576];        // 18,432 B: per-wave meta, then store buffer
    // total 73,728 B -> still 2 blocks/CU at launch_bounds(512,4)

    const int tid  = threadIdx.x;
    const int lane = tid & 63;
    const int wave = tid >> 6;                 // 0..7
    const int m    = lane & 15;
    const int quad = lane >> 4;

    // ---- bijective XCD-chunked swizzle (m204 form): grid=782, 8 XCDs, q=97, r=6 ----
    // Default mapping round-robins consecutive blocks across XCDs -> every XCD's gather
    // working set is the whole 6.4MB feature array (> 4MiB L2). Chunked mapping gives
    // each XCD a contiguous voxel slab (~1.7MB neighborhood) -> gathers become L2 hits.
    const int bid  = blockIdx.x;
    const int xcd  = bid & 7;
    const int bi   = bid >> 3;
    const int bswz = (xcd < 6) ? xcd * 98 + bi : 588 + (xcd - 6) * 97 + bi;

    const int tile0 = bswz * 8 + wave;         // 16 voxels per wave
    const bool tv   = tile0 < NTILE;
    const int tile  = tv ? tile0 : (NTILE - 1); // clamp whole wave (no OOB, no store)
    const int v0    = tile * 16;

    // ---- weight fragment prefetch to registers (VMEM in flight during meta phase) ----
    short8 wreg[7];
#pragma unroll
    for (int u = 0; u < 7; ++u) {
        int g = tid + u * 512;
        if (g < KOFF * 2 * 64) wreg[u] = wfrag[g];
    }

    // ---- Phase A: wave-coalesced metadata load -> enc -> per-wave LDS region ----
    // Tile metadata = 432 contiguous ints per array (16B-aligned base). Non-temporal:
    // single-use stream, keep it out of L2 so feature rows stay resident.
    int* meta = mstore + wave * 576;           // 16 rows x 28 ints (448 used of 576)
    {
        const int tb = v0 * KOFF;
        const int j0 = lane * 4;
        int4v ia = __builtin_nontemporal_load((const int4v*)(nbr_idx  + tb + j0));
        int4v ma = __builtin_nontemporal_load((const int4v*)(nbr_mask + tb + j0));
#pragma unroll
        for (int c = 0; c < 4; ++c) {
            int j = j0 + c;                    // 0..255
            meta[(j / 27) * 28 + (j % 27)] = (ma[c] ? ia[c] : NVOX) << 6;
        }
        if (j0 < 176) {                        // lanes 0..43 cover j = 256..431
            int4v ib = __builtin_nontemporal_load((const int4v*)(nbr_idx  + tb + 256 + j0));
            int4v mb = __builtin_nontemporal_load((const int4v*)(nbr_mask + tb + 256 + j0));
#pragma unroll
            for (int c = 0; c < 4; ++c) {
                int j = 256 + j0 + c;
                meta[(j / 27) * 28 + (j % 27)] = (mb[c] ? ib[c] : NVOX) << 6;
            }
        }
    }

    // readback own voxel's 27 enc values (wave-local write->read; in-order DS pipe)
    int enc[28];
    {
        const int4v* mp = (const int4v*)(meta + m * 28);   // 16B-aligned, 2-way bank alias (free)
#pragma unroll
        for (int i = 0; i < 7; ++i) {
            int4v t = mp[i];
            enc[i * 4 + 0] = t.x; enc[i * 4 + 1] = t.y;
            enc[i * 4 + 2] = t.z; enc[i * 4 + 3] = t.w;
        }
    }

    // ---- sparsity bitmask: bit k set iff ANY of the wave's 16 voxels has an active k-neighbor ----
    unsigned bmv = 0;
#pragma unroll
    for (int k = 0; k < KOFF; ++k)
        bmv |= (__any(enc[k] != SENTE) ? 1u : 0u) << k;
    const unsigned bm = (unsigned)__builtin_amdgcn_readfirstlane((int)bmv);

    // ---- weight regs -> LDS (wreg dead after this), then the ONLY barrier ----
#pragma unroll
    for (int u = 0; u < 7; ++u) {
        int g = tid + u * 512;
        if (g < KOFF * 2 * 64) wlds[g] = wreg[u];
    }

    const char* fb   = (const char*)fbf;
    const int   boff = quad * 16;              // byte offset of A-frag in row

    // depth-8 gather prologue issued before the barrier: latency overlaps barrier wait
    short8 abuf[8];
#pragma unroll
    for (int k = 0; k < 8; ++k)
        abuf[k] = *(const short8*)(fb + (size_t)(unsigned)enc[k] + boff);

    __syncthreads();                           // all weight writes visible

    float4v acc0 = {0.f, 0.f, 0.f, 0.f};
    float4v acc1 = {0.f, 0.f, 0.f, 0.f};

    // ---- depth-8 rotating gather pipeline, fully unrolled (static slots) ----
    // Gathers unconditional: inactive-k gathers hit the single zero row (L1-hit).
#pragma unroll
    for (int k = 0; k < KOFF; ++k) {
        const int slot = k & 7;
        short8 a = abuf[slot];
        if (k + 8 < KOFF)
            abuf[slot] = *(const short8*)(fb + (size_t)(unsigned)enc[k + 8] + boff);

        if (bm & (1u << k)) {                  // wave-uniform scalar branch
            short8 wb0 = wlds[k * 128 + lane];
            short8 wb1 = wlds[k * 128 + 64 + lane];
            acc0 = __builtin_amdgcn_mfma_f32_16x16x32_bf16(a, wb0, acc0, 0, 0, 0);
            acc1 = __builtin_amdgcn_mfma_f32_16x16x32_bf16(a, wb1, acc1, 0, 0, 0);
        }
    }

    // ---- coalesced epilogue: transpose through per-wave meta region (dead since
    // before the barrier -> NO second barrier needed; wave-local write->read). ----
    float* tb = (float*)(mstore + wave * 576);     // 16 rows, stride 36 (2-way banks)

    const float bs0 = bias[m];
    const float bs1 = bias[16 + m];
    if (tv) {
        // C/D layout: col (cout) = lane&15, row (voxel) = quad*4 + reg
#pragma unroll
        for (int r = 0; r < 4; ++r) {
            tb[(quad * 4 + r) * 36 + m]      = acc0[r] + bs0;
            tb[(quad * 4 + r) * 36 + 16 + m] = acc1[r] + bs1;
        }
#pragma unroll
        for (int p = 0; p < 2; ++p) {
            int flat = p * 64 + lane;          // 0..127
            int row  = flat >> 3;              // 8 lanes per 128B row
            int ch   = flat & 7;               // 16B chunk within row
            float4v val = *(const float4v*)(tb + row * 36 + ch * 4);
            // output is write-once, never re-read -> non-temporal, keep L2 for gathers
            __builtin_nontemporal_store(val, (float4v*)(out + (size_t)(v0 + row) * COUT + ch * 4));
        }
    }
}

extern "C" void kernel_launch(void* const* d_in, const int* in_sizes, int n_in,
                              void* d_out, int out_size, void* d_ws, size_t ws_size,
                              hipStream_t stream) {
    const float* feat = (const float*)d_in[0];
    const float* wgt  = (const float*)d_in[1];
    const float* bias = (const float*)d_in[2];
    const int*   nidx = (const int*)d_in[3];
    const int*   nmsk = (const int*)d_in[4];
    float*       out  = (float*)d_out;

    char* ws = (char*)d_ws;
    unsigned short* fbf   = (unsigned short*)ws;                 // 6,400,064 B
    short8*         wfrag = (short8*)(ws + 6400128);             //    55,296 B

    const int wgt_blocks = (KOFF * 2 * 64 + 255) / 256;          // 14
    cvt_kernel<<<FEAT_BLOCKS + wgt_blocks, 256, 0, stream>>>(feat, wgt, fbf, wfrag);

    const int block = 512;                         // 8 waves = 8 tiles = 128 voxels
    const int grid  = (NTILE + 7) / 8;             // 782
    subm_conv_kernel<<<grid, block, 0, stream>>>(fbf, wfrag, bias, nidx, nmsk, out);
}